// Round 7
// baseline (8117.407 us; speedup 1.0000x reference)
//
#include <hip/hip_runtime.h>
#include <hip/hip_bf16.h>

using bf16 = __hip_bfloat16;
typedef __attribute__((ext_vector_type(8))) short short8;
typedef __attribute__((ext_vector_type(4))) float f32x4;

static __device__ __forceinline__ float b2f(unsigned short s) {
    unsigned u = ((unsigned)s) << 16;
    return __builtin_bit_cast(float, u);
}
static __device__ __forceinline__ short f2b(float f) {
    __hip_bfloat16 h = __float2bfloat16(f);
    return __builtin_bit_cast(short, h);
}

// ---------------- f32 -> bf16 conversion (8 elems/thread) ----------------
__global__ void f32_to_bf16_vec(const float* __restrict__ in, bf16* __restrict__ out, int n8) {
    int i = blockIdx.x * blockDim.x + threadIdx.x;
    if (i >= n8) return;
    const f32x4* p = (const f32x4*)(in + (size_t)i * 8);
    f32x4 a = p[0], b = p[1];
    short8 o;
    o[0] = f2b(a[0]); o[1] = f2b(a[1]); o[2] = f2b(a[2]); o[3] = f2b(a[3]);
    o[4] = f2b(b[0]); o[5] = f2b(b[1]); o[6] = f2b(b[2]); o[7] = f2b(b[3]);
    *(short8*)(out + (size_t)i * 8) = o;
}

// ---------------- GEMM: C = act(X @ W^T + bias), bf16 in/out ----------------
template<int K, bool RELU>
__global__ __launch_bounds__(256) void gemm_xwt(
    const bf16* __restrict__ X, const bf16* __restrict__ W,
    const float* __restrict__ bias, bf16* __restrict__ C, int Nout)
{
    __shared__ bf16 As[128][40];
    __shared__ bf16 Bs[128][40];
    const int tid  = threadIdx.x;
    const int wave = tid >> 6, lane = tid & 63;
    const int wr = wave >> 1, wc = wave & 1;
    const long Mbase = (long)blockIdx.x * 128;
    const int  Nbase = blockIdx.y * 128;
    const int kg = (lane >> 4) * 8;

    f32x4 acc[4][4];
#pragma unroll
    for (int i = 0; i < 4; ++i)
#pragma unroll
        for (int j = 0; j < 4; ++j) acc[i][j] = (f32x4){0.f, 0.f, 0.f, 0.f};

    for (int kb = 0; kb < K / 32; ++kb) {
        __syncthreads();
#pragma unroll
        for (int q = 0; q < 2; ++q) {
            int idx = q * 256 + tid;
            int row = idx >> 2, kp = (idx & 3) * 8;
            *(short8*)&As[row][kp] = *(const short8*)&X[(Mbase + row) * K + kb * 32 + kp];
            *(short8*)&Bs[row][kp] = *(const short8*)&W[(long)(Nbase + row) * K + kb * 32 + kp];
        }
        __syncthreads();
        short8 a[4], b[4];
#pragma unroll
        for (int mt = 0; mt < 4; ++mt)
            a[mt] = *(const short8*)&As[wr * 64 + mt * 16 + (lane & 15)][kg];
#pragma unroll
        for (int nt = 0; nt < 4; ++nt)
            b[nt] = *(const short8*)&Bs[wc * 64 + nt * 16 + (lane & 15)][kg];
#pragma unroll
        for (int mt = 0; mt < 4; ++mt)
#pragma unroll
            for (int nt = 0; nt < 4; ++nt)
                acc[mt][nt] = __builtin_amdgcn_mfma_f32_16x16x32_bf16(a[mt], b[nt], acc[mt][nt], 0, 0, 0);
    }

#pragma unroll
    for (int mt = 0; mt < 4; ++mt) {
        int row0 = wr * 64 + mt * 16 + (lane >> 4) * 4;
#pragma unroll
        for (int nt = 0; nt < 4; ++nt) {
            int col = Nbase + wc * 64 + nt * 16 + (lane & 15);
            float bv = bias[col];
#pragma unroll
            for (int r = 0; r < 4; ++r) {
                float v = acc[mt][nt][r] + bv;
                if (RELU) v = fmaxf(v, 0.f);
                C[(Mbase + row0 + r) * (long)Nout + col] = __float2bfloat16(v);
            }
        }
    }
}

// ---------------- LayerNorm rows of 512, bf16 -> bf16 ----------------
__global__ __launch_bounds__(256) void ln_rows512(
    const bf16* __restrict__ in, bf16* __restrict__ out,
    const float* __restrict__ g, const float* __restrict__ be)
{
    const int lane = threadIdx.x & 63;
    const long row = (long)blockIdx.x * 4 + (threadIdx.x >> 6);
    const bf16* rp = in + row * 512;
    short8 v = *(const short8*)&rp[lane * 8];
    float x[8]; float s = 0.f, sq = 0.f;
#pragma unroll
    for (int j = 0; j < 8; ++j) { x[j] = b2f((unsigned short)v[j]); s += x[j]; sq += x[j] * x[j]; }
#pragma unroll
    for (int m = 1; m < 64; m <<= 1) { s += __shfl_xor(s, m); sq += __shfl_xor(sq, m); }
    float mu   = s * (1.f / 512.f);
    float var  = sq * (1.f / 512.f) - mu * mu;
    float rstd = rsqrtf(var + 1e-5f);
    short8 o;
#pragma unroll
    for (int j = 0; j < 8; ++j) {
        int c = lane * 8 + j;
        o[j] = f2b((x[j] - mu) * rstd * g[c] + be[c]);
    }
    *(short8*)(out + row * 512 + lane * 8) = o;
}

// ---------------- GRU scan v7: 512 threads, full register budget, global-B ----------------
// 32 blocks x 16 batch rows; 8 waves (2/SIMD via __launch_bounds__(512,2) => 256 regs/lane).
// Wave w owns h-cols [64w,64w+64) for all 3 gates: 12 gh col-tiles of 16.
// B-frags read directly from global Whh (each (row,kc): 4 kg-groups consume one 64B line);
// no inline asm, no LDS staging for B -- compiler pipelines, L2 holds Whh.
// h master f32 in regs (16/lane); h exchanged via LDS hb (pre-masked bf16); fused LN.
__global__ __launch_bounds__(512, 2) void gru_scan7(
    const bf16* __restrict__ gi, const float* __restrict__ on_reset,
    const float* __restrict__ hx, const bf16* __restrict__ Whh,
    const float* __restrict__ bhh, const float* __restrict__ gr,
    const float* __restrict__ br, float* __restrict__ out, float* __restrict__ hT)
{
    __shared__ bf16  hb[16][520];      // bf16 h (pre-masked), row stride 1040B
    __shared__ float lnS[16][8];       // [row][wave] partial sums
    __shared__ float lnQ[16][8];

    const int tid = threadIdx.x;
    const int w   = tid >> 6, lane = tid & 63;
    const int lc  = lane & 15, kg = lane >> 4;
    const int n0  = blockIdx.x * 16;
    const int cw0 = w * 64;

    // ---- hoisted per-lane constants (4 owned h-cols x 3 gates) ----
    float bhr[4], bhz[4], bhn[4], grg[4], brb[4];
#pragma unroll
    for (int cj = 0; cj < 4; ++cj) {
        const int col = cw0 + cj * 16 + lc;
        bhr[cj] = bhh[col];
        bhz[cj] = bhh[512 + col];
        bhn[cj] = bhh[1024 + col];
        grg[cj] = gr[col];
        brb[cj] = br[col];
    }

    // ---- h master init + hb(0) ----
    float hreg[4][4];   // [cj][r]
#pragma unroll
    for (int r = 0; r < 4; ++r) {
        const int row = kg * 4 + r;
        const float m0 = on_reset[n0 + row];
#pragma unroll
        for (int cj = 0; cj < 4; ++cj) {
            const int col = cw0 + cj * 16 + lc;
            float v = hx[(size_t)(n0 + row) * 512 + col];
            hreg[cj][r] = v;
            hb[row][col] = __float2bfloat16(v * m0);
        }
    }
    __syncthreads();

#pragma unroll 1
    for (int t = 0; t < 128; ++t) {
        // [A] masks for t and t+1
        float mcur[4], mnx[4];
#pragma unroll
        for (int r = 0; r < 4; ++r) {
            const int row = kg * 4 + r;
            mcur[r] = on_reset[(size_t)t * 512 + n0 + row];
            mnx[r]  = (t < 127) ? on_reset[(size_t)(t + 1) * 512 + n0 + row] : 1.f;
        }

        // [B] A-frags from hb (kept in regs for the whole step)
        short8 aF[16];
#pragma unroll
        for (int kc = 0; kc < 16; ++kc)
            aF[kc] = *(const short8*)&hb[lc][kc * 32 + kg * 8];

        // [S] gh = (h*m) @ Whh^T for this wave's 12 col-tiles; B direct from global
        f32x4 acc[12];
#pragma unroll
        for (int ct = 0; ct < 12; ++ct) {
            const int col16 = (ct >> 2) * 512 + cw0 + (ct & 3) * 16;
            const bf16* wp = Whh + (((size_t)(col16 + lc)) << 9) + kg * 8;
            short8 bq[16];
#pragma unroll
            for (int kc = 0; kc < 16; ++kc)
                bq[kc] = *(const short8*)&wp[kc * 32];
            f32x4 a = (f32x4){0.f, 0.f, 0.f, 0.f};
#pragma unroll
            for (int kc = 0; kc < 16; ++kc)
                a = __builtin_amdgcn_mfma_f32_16x16x32_bf16(aF[kc], bq[kc], a, 0, 0, 0);
            acc[ct] = a;
        }

        // [C] LN-finalize(t-1) + coalesced out stores
        if (t > 0) {
#pragma unroll
            for (int r = 0; r < 4; ++r) {
                const int row = kg * 4 + r;
                f32x4 vs0 = *(const f32x4*)&lnS[row][0];
                f32x4 vs1 = *(const f32x4*)&lnS[row][4];
                f32x4 vq0 = *(const f32x4*)&lnQ[row][0];
                f32x4 vq1 = *(const f32x4*)&lnQ[row][4];
                float s = vs0[0] + vs0[1] + vs0[2] + vs0[3] + vs1[0] + vs1[1] + vs1[2] + vs1[3];
                float q = vq0[0] + vq0[1] + vq0[2] + vq0[3] + vq1[0] + vq1[1] + vq1[2] + vq1[3];
                const float mu   = s * (1.f / 512.f);
                const float var  = q * (1.f / 512.f) - mu * mu;
                const float rstd = rsqrtf(var + 1e-5f);
                float* orow = out + ((size_t)(t - 1) * 512 + n0 + row) * 512;
#pragma unroll
                for (int cj = 0; cj < 4; ++cj) {
                    const int col = cw0 + cj * 16 + lc;
                    float o = (hreg[cj][r] - mu) * rstd * grg[cj] + brb[cj];
                    __builtin_nontemporal_store(o, orow + col);
                }
            }
        }

        __syncthreads();   // [D] hb(t) reads done; lnS(t-1) reads done

        // [E] gates: gi NT loads, update h, write hb(t+1), LN partials(t)
        {
            float sacc[4], qacc[4];
#pragma unroll
            for (int r = 0; r < 4; ++r) {
                const int row = kg * 4 + r;
                const unsigned short* gp =
                    (const unsigned short*)gi + ((size_t)t * 512 + n0 + row) * 1536;
                float sc = 0.f, qc = 0.f;
#pragma unroll
                for (int cj = 0; cj < 4; ++cj) {
                    const int col = cw0 + cj * 16 + lc;
                    const float ir  = b2f(__builtin_nontemporal_load(gp + col));
                    const float iz  = b2f(__builtin_nontemporal_load(gp + 512 + col));
                    const float inn = b2f(__builtin_nontemporal_load(gp + 1024 + col));
                    const float hr = acc[0 + cj][r] + bhr[cj];
                    const float hz = acc[4 + cj][r] + bhz[cj];
                    const float hn = acc[8 + cj][r] + bhn[cj];
                    const float rg = 1.f / (1.f + __expf(-(ir + hr)));
                    const float zg = 1.f / (1.f + __expf(-(iz + hz)));
                    const float e2 = __expf(2.f * (inn + rg * hn));
                    const float ng = 1.f - 2.f / (e2 + 1.f);   // tanh
                    const float hv = (1.f - zg) * ng + zg * (hreg[cj][r] * mcur[r]);
                    hreg[cj][r] = hv;
                    hb[row][col] = __float2bfloat16(hv * mnx[r]);
                    sc += hv; qc += hv * hv;
                }
                sacc[r] = sc; qacc[r] = qc;
            }
#pragma unroll
            for (int m = 1; m < 16; m <<= 1)
#pragma unroll
                for (int r = 0; r < 4; ++r) {
                    sacc[r] += __shfl_xor(sacc[r], m);
                    qacc[r] += __shfl_xor(qacc[r], m);
                }
            if (lc == 0) {
#pragma unroll
                for (int r = 0; r < 4; ++r) {
                    lnS[kg * 4 + r][w] = sacc[r];
                    lnQ[kg * 4 + r][w] = qacc[r];
                }
            }
        }

        __syncthreads();   // [F] hb(t+1), lnS(t) visible
    }

    // ---- epilogue: LN-finalize(127) + hT ----
#pragma unroll
    for (int r = 0; r < 4; ++r) {
        const int row = kg * 4 + r;
        f32x4 vs0 = *(const f32x4*)&lnS[row][0];
        f32x4 vs1 = *(const f32x4*)&lnS[row][4];
        f32x4 vq0 = *(const f32x4*)&lnQ[row][0];
        f32x4 vq1 = *(const f32x4*)&lnQ[row][4];
        float s = vs0[0] + vs0[1] + vs0[2] + vs0[3] + vs1[0] + vs1[1] + vs1[2] + vs1[3];
        float q = vq0[0] + vq0[1] + vq0[2] + vq0[3] + vq1[0] + vq1[1] + vq1[2] + vq1[3];
        const float mu   = s * (1.f / 512.f);
        const float var  = q * (1.f / 512.f) - mu * mu;
        const float rstd = rsqrtf(var + 1e-5f);
        float* orow = out + ((size_t)127 * 512 + n0 + row) * 512;
#pragma unroll
        for (int cj = 0; cj < 4; ++cj) {
            const int col = cw0 + cj * 16 + lc;
            float o = (hreg[cj][r] - mu) * rstd * grg[cj] + brb[cj];
            __builtin_nontemporal_store(o, orow + col);
            hT[(size_t)(n0 + row) * 512 + col] = hreg[cj][r];
        }
    }
}

// ---------------- launch ----------------
extern "C" void kernel_launch(void* const* d_in, const int* in_sizes, int n_in,
                              void* d_out, int out_size, void* d_ws, size_t ws_size,
                              hipStream_t stream) {
    const float* obs      = (const float*)d_in[0];
    const float* hx       = (const float*)d_in[1];
    const float* on_reset = (const float*)d_in[2];
    const float* W1  = (const float*)d_in[3];
    const float* b1  = (const float*)d_in[4];
    const float* g1  = (const float*)d_in[5];
    const float* be1 = (const float*)d_in[6];
    const float* W2  = (const float*)d_in[7];
    const float* b2  = (const float*)d_in[8];
    const float* g2  = (const float*)d_in[9];
    const float* be2 = (const float*)d_in[10];
    const float* Wih = (const float*)d_in[11];
    const float* Whh = (const float*)d_in[12];
    const float* bih = (const float*)d_in[13];
    const float* bhh = (const float*)d_in[14];
    const float* gr  = (const float*)d_in[15];
    const float* br  = (const float*)d_in[16];

    // workspace layout (bytes) — proven 272,236,544 footprint
    char* ws = (char*)d_ws;
    bf16* W1b  = (bf16*)(ws + 0);                    //   131072
    bf16* W2b  = (bf16*)(ws + 131072);               //   524288
    bf16* Wihb = (bf16*)(ws + 655360);               //  1572864
    bf16* Whhb = (bf16*)(ws + 2228224);              //  1572864
    bf16* Y    = (bf16*)(ws + 3801088);              // 67108864  (post-LN acts)
    bf16* GI   = (bf16*)(ws + 3801088 + 67108864);   // 201326592 (gi)
    bf16* X1   = GI;                                 // alias: pre-LN acts (dead before GI)
    bf16* OBSB = (bf16*)((char*)GI + 67108864);      // alias: obs bf16 (dead before GI)

    // conversions
    f32_to_bf16_vec<<<(1048576 + 255) / 256, 256, 0, stream>>>(obs, OBSB, 1048576);
    f32_to_bf16_vec<<<(8192 + 255) / 256,  256, 0, stream>>>(W1,  W1b,  8192);
    f32_to_bf16_vec<<<(32768 + 255) / 256, 256, 0, stream>>>(W2,  W2b,  32768);
    f32_to_bf16_vec<<<(98304 + 255) / 256, 256, 0, stream>>>(Wih, Wihb, 98304);
    f32_to_bf16_vec<<<(98304 + 255) / 256, 256, 0, stream>>>(Whh, Whhb, 98304);

    // MLP + gi
    gemm_xwt<128, true><<<dim3(512, 4), 256, 0, stream>>>(OBSB, W1b, b1, X1, 512);
    ln_rows512<<<16384, 256, 0, stream>>>(X1, Y, g1, be1);
    gemm_xwt<512, true><<<dim3(512, 4), 256, 0, stream>>>(Y, W2b, b2, X1, 512);
    ln_rows512<<<16384, 256, 0, stream>>>(X1, Y, g2, be2);
    gemm_xwt<512, false><<<dim3(512, 12), 256, 0, stream>>>(Y, Wihb, bih, GI, 1536);

    // GRU scan (512 threads, 256 regs/lane, global-B) + fused final LN + hT
    float* out_p = (float*)d_out;
    float* hT_p  = out_p + (size_t)65536 * 512;
    gru_scan7<<<32, 512, 0, stream>>>(GI, on_reset, hx, Whhb, bhh, gr, br, out_p, hT_p);
}